// Round 1
// baseline (472.282 us; speedup 1.0000x reference)
//
#include <hip/hip_runtime.h>
#include <hip/hip_bf16.h>

#define BH 64
#define NKV 8192
#define NQ 2048
#define DIM 128
#define EPSV 1e-6f

typedef __attribute__((ext_vector_type(8))) short bf16x8;
typedef __attribute__((ext_vector_type(4))) float f32x4;

__device__ __forceinline__ float phi_f(float x) { return x > 0.f ? x + 1.f : __expf(x); }

__device__ __forceinline__ ushort f2bf(float f) {
  unsigned u = __builtin_bit_cast(unsigned, f);
  u += 0x7FFFu + ((u >> 16) & 1u);   // round-to-nearest-even
  return (ushort)(u >> 16);
}
__device__ __forceinline__ float bf2f(ushort h) {
  unsigned u = ((unsigned)h) << 16;
  return __builtin_bit_cast(float, u);
}

// ---------------- Kernel 1: partial KV = phi(K)^T V and partial Z ------------
#define KT 32
#define LDK 40   // 32 + 8 pad (bf16); row=80B: conflict-light reads, b128-aligned

__global__ __launch_bounds__(256) void k1_kv(
    const float* __restrict__ Kg, const float* __restrict__ Vg,
    float* __restrict__ part, float* __restrict__ zpart, int nch, int ck)
{
  __shared__ ushort ktl[DIM * LDK];
  __shared__ ushort vtl[DIM * LDK];
  __shared__ float zl[DIM];

  const int wg = blockIdx.x;
  const int bh = wg / nch;
  const int c  = wg - bh * nch;
  const int t  = threadIdx.x;
  const int lane = t & 63;
  const int w  = t >> 6;          // wave 0..3 -> e range w*32..w*32+32
  const int p  = t >> 4;          // row-pair 0..15
  const int db = (t & 15) * 8;    // d base for staging

  const long base = (long)bh * NKV * DIM + (long)c * ck * DIM;
  const float* Kp = Kg + base;
  const float* Vp = Vg + base;

  if (t < DIM) zl[t] = 0.f;
  __syncthreads();

  f32x4 acc[8][2];
#pragma unroll
  for (int i = 0; i < 8; i++) {
    acc[i][0] = (f32x4){0.f, 0.f, 0.f, 0.f};
    acc[i][1] = (f32x4){0.f, 0.f, 0.f, 0.f};
  }
  float zacc[8];
#pragma unroll
  for (int j = 0; j < 8; j++) zacc[j] = 0.f;

  const int kk = (lane >> 4) * 8;

  for (int k0 = 0; k0 < ck; k0 += KT) {
    const float* kr = Kp + (long)(k0 + 2 * p) * DIM + db;
    float4 ka0 = *(const float4*)(kr);
    float4 ka1 = *(const float4*)(kr + 4);
    float4 kb0 = *(const float4*)(kr + DIM);
    float4 kb1 = *(const float4*)(kr + DIM + 4);
    const float* vr = Vp + (long)(k0 + 2 * p) * DIM + db;
    float4 va0 = *(const float4*)(vr);
    float4 va1 = *(const float4*)(vr + 4);
    float4 vb0 = *(const float4*)(vr + DIM);
    float4 vb1 = *(const float4*)(vr + DIM + 4);

    float k0a[8] = {ka0.x, ka0.y, ka0.z, ka0.w, ka1.x, ka1.y, ka1.z, ka1.w};
    float k1a[8] = {kb0.x, kb0.y, kb0.z, kb0.w, kb1.x, kb1.y, kb1.z, kb1.w};
    float v0a[8] = {va0.x, va0.y, va0.z, va0.w, va1.x, va1.y, va1.z, va1.w};
    float v1a[8] = {vb0.x, vb0.y, vb0.z, vb0.w, vb1.x, vb1.y, vb1.z, vb1.w};

    __syncthreads();   // previous iteration's LDS reads done

#pragma unroll
    for (int j = 0; j < 8; j++) {
      ushort a = f2bf(phi_f(k0a[j]));
      ushort b = f2bf(phi_f(k1a[j]));
      zacc[j] += bf2f(a) + bf2f(b);   // Z consistent with bf16-rounded MFMA operand
      *(unsigned*)&ktl[(db + j) * LDK + 2 * p] = (unsigned)a | ((unsigned)b << 16);
      ushort x = f2bf(v0a[j]);
      ushort y = f2bf(v1a[j]);
      *(unsigned*)&vtl[(db + j) * LDK + 2 * p] = (unsigned)x | ((unsigned)y << 16);
    }
    __syncthreads();

    bf16x8 bfr[2];
#pragma unroll
    for (int et = 0; et < 2; et++) {
      int e = w * 32 + et * 16 + (lane & 15);
      bfr[et] = *(const bf16x8*)&vtl[e * LDK + kk];
    }
#pragma unroll
    for (int dt = 0; dt < 8; dt++) {
      int dd = dt * 16 + (lane & 15);
      bf16x8 afr = *(const bf16x8*)&ktl[dd * LDK + kk];
      acc[dt][0] = __builtin_amdgcn_mfma_f32_16x16x32_bf16(afr, bfr[0], acc[dt][0], 0, 0, 0);
      acc[dt][1] = __builtin_amdgcn_mfma_f32_16x16x32_bf16(afr, bfr[1], acc[dt][1], 0, 0, 0);
    }
  }

  // write partial KV [d][e] f32
  float* pp = part + (long)wg * (DIM * DIM);
#pragma unroll
  for (int dt = 0; dt < 8; dt++) {
#pragma unroll
    for (int et = 0; et < 2; et++) {
      int e = w * 32 + et * 16 + (lane & 15);
      int r0 = dt * 16 + (lane >> 4) * 4;
#pragma unroll
      for (int r = 0; r < 4; r++)
        pp[(r0 + r) * DIM + e] = acc[dt][et][r];
    }
  }
#pragma unroll
  for (int j = 0; j < 8; j++) atomicAdd(&zl[db + j], zacc[j]);
  __syncthreads();
  if (t < DIM) zpart[(long)wg * DIM + t] = zl[t];
}

// ------------- Reduce: sum partials, emit KV^T (bf16) and Z (f32) -----------
__global__ __launch_bounds__(256) void k_red(
    const float* __restrict__ part, const float* __restrict__ zpart,
    ushort* __restrict__ kvt, float* __restrict__ zout, int nch)
{
  __shared__ float kl[64 * 129];
  const int bh = blockIdx.x;
  const int t = threadIdx.x;
  const long pbase = (long)bh * nch * (DIM * DIM);

  for (int h = 0; h < 2; h++) {
    __syncthreads();
#pragma unroll 4
    for (int i = 0; i < 32; i++) {
      int il = t + i * 256;          // 0..8191, input idx (d_local*128+e)
      long idx = pbase + h * 8192 + il;
      float s = 0.f;
      for (int cc = 0; cc < nch; cc++) s += part[idx + (long)cc * (DIM * DIM)];
      int dl = il >> 7;
      int e  = il & 127;
      kl[dl * 129 + e] = s;
    }
    __syncthreads();
#pragma unroll 4
    for (int i = 0; i < 32; i++) {
      int il = t + i * 256;          // e*64 + dl
      int e = il >> 6, dl = il & 63;
      kvt[(long)bh * (DIM * DIM) + e * DIM + h * 64 + dl] = f2bf(kl[dl * 129 + e]);
    }
  }
  if (t < DIM) {
    float s = 0.f;
    for (int cc = 0; cc < nch; cc++) s += zpart[((long)bh * nch + cc) * DIM + t];
    zout[(long)bh * DIM + t] = s;
  }
}

// --------- Kernel 2: out = (phi(Q) KV) / (phi(Q)·Z + eps) -------------------
#define QB 64
#define LDQ 136   // 128 + 8 pad

__global__ __launch_bounds__(256) void k2_fwd(
    const float* __restrict__ Qg, const ushort* __restrict__ kvt,
    const float* __restrict__ zg, float* __restrict__ outg)
{
  __shared__ ushort ql[QB * LDQ];
  __shared__ ushort kvl[DIM * LDQ];
  __shared__ float zl[DIM];
  __shared__ float dpart[4][QB];
  __shared__ float invd[QB];

  const int bid = blockIdx.x;
  const int bh = bid >> 5;
  const int q0 = (bid & 31) * QB;
  const int t = threadIdx.x;
  const int lane = t & 63;
  const int w = t >> 6;

  if (t < DIM) zl[t] = zg[(long)bh * DIM + t];

  // stage phi(Q) as bf16, row-major
  const float* Qp = Qg + ((long)bh * NQ + q0) * DIM;
#pragma unroll
  for (int i = 0; i < 8; i++) {
    int idx4 = t + i * 256;          // float4 chunk id
    int row = idx4 >> 5;
    int c4 = idx4 & 31;
    float4 v = *(const float4*)(Qp + (long)row * DIM + c4 * 4);
    ushort a = f2bf(phi_f(v.x)), b = f2bf(phi_f(v.y));
    ushort cq = f2bf(phi_f(v.z)), dq = f2bf(phi_f(v.w));
    uint2 pk;
    pk.x = (unsigned)a | ((unsigned)b << 16);
    pk.y = (unsigned)cq | ((unsigned)dq << 16);
    *(uint2*)&ql[row * LDQ + c4 * 4] = pk;
  }
  // stage KV^T (already bf16)
  const ushort* kp = kvt + (long)bh * (DIM * DIM);
#pragma unroll
  for (int i = 0; i < 8; i++) {
    int idx8 = t + i * 256;
    int row = idx8 >> 4;
    int c8 = idx8 & 15;
    uint4 vv = *(const uint4*)(kp + row * DIM + c8 * 8);
    *(uint4*)&kvl[row * LDQ + c8 * 8] = vv;
  }
  __syncthreads();

  // denominator per row
  {
    int row = t & (QB - 1);
    int q4 = t >> 6;
    float s = 0.f;
#pragma unroll
    for (int i = 0; i < 4; i++) {
      int d0 = q4 * 32 + i * 8;
      bf16x8 qv = *(const bf16x8*)&ql[row * LDQ + d0];
#pragma unroll
      for (int j = 0; j < 8; j++)
        s += bf2f((ushort)qv[j]) * zl[d0 + j];
    }
    dpart[q4][row] = s;
  }
  __syncthreads();
  if (t < QB) {
    float den = dpart[0][t] + dpart[1][t] + dpart[2][t] + dpart[3][t] + EPSV;
    invd[t] = 1.f / den;
  }
  __syncthreads();

  // numerator via MFMA: D[q][e] += A[q][d] * B[d][e]
  const int kk = (lane >> 4) * 8;
  const int qrow = w * 16 + (lane & 15);
  f32x4 acc[8];
#pragma unroll
  for (int et = 0; et < 8; et++) acc[et] = (f32x4){0.f, 0.f, 0.f, 0.f};

#pragma unroll
  for (int d0 = 0; d0 < DIM; d0 += 32) {
    bf16x8 afr = *(const bf16x8*)&ql[qrow * LDQ + d0 + kk];
#pragma unroll
    for (int et = 0; et < 8; et++) {
      int e = et * 16 + (lane & 15);
      bf16x8 bfr = *(const bf16x8*)&kvl[e * LDQ + d0 + kk];
      acc[et] = __builtin_amdgcn_mfma_f32_16x16x32_bf16(afr, bfr, acc[et], 0, 0, 0);
    }
  }

  // epilogue: scale by 1/den, store f32
  float* op = outg + ((long)bh * NQ + q0) * DIM;
#pragma unroll
  for (int et = 0; et < 8; et++) {
    int e = et * 16 + (lane & 15);
    int r0 = w * 16 + (lane >> 4) * 4;
#pragma unroll
    for (int r = 0; r < 4; r++) {
      float val = acc[et][r] * invd[r0 + r];
      op[(long)(r0 + r) * DIM + e] = val;
    }
  }
}

extern "C" void kernel_launch(void* const* d_in, const int* in_sizes, int n_in,
                              void* d_out, int out_size, void* d_ws, size_t ws_size,
                              hipStream_t stream) {
  const float* Q  = (const float*)d_in[0];
  const float* Km = (const float*)d_in[1];
  const float* Vm = (const float*)d_in[2];
  float* out = (float*)d_out;

  char* ws = (char*)d_ws;
  ushort* kvt = (ushort*)ws;                                    // 64*16384*2 = 2 MB
  float* zred = (float*)(ws + (size_t)BH * DIM * DIM * 2);      // 32 KB
  size_t fixed = (size_t)BH * DIM * DIM * 2 + (size_t)BH * DIM * 4;

  int nch = 16;
  while (nch > 1) {
    size_t need = fixed + (size_t)BH * nch * DIM * DIM * 4 + (size_t)BH * nch * DIM * 4;
    if (need <= ws_size) break;
    nch >>= 1;
  }
  float* part  = (float*)(ws + fixed);
  float* zpart = part + (size_t)BH * nch * DIM * DIM;
  int ck = NKV / nch;

  k1_kv<<<BH * nch, 256, 0, stream>>>(Km, Vm, part, zpart, nch, ck);
  k_red<<<BH, 256, 0, stream>>>(part, zpart, kvt, zred, nch);
  k2_fwd<<<BH * 32, 256, 0, stream>>>(Q, kvt, zred, out);
}

// Round 2
// 195.264 us; speedup vs baseline: 2.4187x; 2.4187x over previous
//
#include <hip/hip_runtime.h>
#include <hip/hip_bf16.h>

#define BH 64
#define NKV 8192
#define NQ 2048
#define DIM 128
#define EPSV 1e-6f

typedef __attribute__((ext_vector_type(8))) short bf16x8;
typedef __attribute__((ext_vector_type(4))) float f32x4;

__device__ __forceinline__ float phi_f(float x) { return x > 0.f ? x + 1.f : __expf(x); }

__device__ __forceinline__ ushort f2bf(float f) {
  unsigned u = __builtin_bit_cast(unsigned, f);
  u += 0x7FFFu + ((u >> 16) & 1u);   // round-to-nearest-even
  return (ushort)(u >> 16);
}
__device__ __forceinline__ float bf2f(ushort h) {
  unsigned u = ((unsigned)h) << 16;
  return __builtin_bit_cast(float, u);
}

// ---------------- Kernel 1: partial KV = phi(K)^T V and partial Z ------------
#define KT 32
#define LDK 40   // 32 + 8 pad (bf16); row=80B: conflict-light reads, b128-aligned

__global__ __launch_bounds__(256) void k1_kv(
    const float* __restrict__ Kg, const float* __restrict__ Vg,
    float* __restrict__ part, float* __restrict__ zpart, int nch, int ck)
{
  __shared__ ushort ktl[DIM * LDK];
  __shared__ ushort vtl[DIM * LDK];
  __shared__ float zl[DIM];

  const int wg = blockIdx.x;
  const int bh = wg / nch;
  const int c  = wg - bh * nch;
  const int t  = threadIdx.x;
  const int lane = t & 63;
  const int w  = t >> 6;          // wave 0..3 -> e range w*32..w*32+32
  const int p  = t >> 4;          // row-pair 0..15
  const int db = (t & 15) * 8;    // d base for staging

  const long base = (long)bh * NKV * DIM + (long)c * ck * DIM;
  const float* Kp = Kg + base;
  const float* Vp = Vg + base;

  if (t < DIM) zl[t] = 0.f;
  __syncthreads();

  f32x4 acc[8][2];
#pragma unroll
  for (int i = 0; i < 8; i++) {
    acc[i][0] = (f32x4){0.f, 0.f, 0.f, 0.f};
    acc[i][1] = (f32x4){0.f, 0.f, 0.f, 0.f};
  }
  float zacc[8];
#pragma unroll
  for (int j = 0; j < 8; j++) zacc[j] = 0.f;

  const int kk = (lane >> 4) * 8;

  for (int k0 = 0; k0 < ck; k0 += KT) {
    const float* kr = Kp + (long)(k0 + 2 * p) * DIM + db;
    float4 ka0 = *(const float4*)(kr);
    float4 ka1 = *(const float4*)(kr + 4);
    float4 kb0 = *(const float4*)(kr + DIM);
    float4 kb1 = *(const float4*)(kr + DIM + 4);
    const float* vr = Vp + (long)(k0 + 2 * p) * DIM + db;
    float4 va0 = *(const float4*)(vr);
    float4 va1 = *(const float4*)(vr + 4);
    float4 vb0 = *(const float4*)(vr + DIM);
    float4 vb1 = *(const float4*)(vr + DIM + 4);

    float k0a[8] = {ka0.x, ka0.y, ka0.z, ka0.w, ka1.x, ka1.y, ka1.z, ka1.w};
    float k1a[8] = {kb0.x, kb0.y, kb0.z, kb0.w, kb1.x, kb1.y, kb1.z, kb1.w};
    float v0a[8] = {va0.x, va0.y, va0.z, va0.w, va1.x, va1.y, va1.z, va1.w};
    float v1a[8] = {vb0.x, vb0.y, vb0.z, vb0.w, vb1.x, vb1.y, vb1.z, vb1.w};

    __syncthreads();   // previous iteration's LDS reads done

#pragma unroll
    for (int j = 0; j < 8; j++) {
      ushort a = f2bf(phi_f(k0a[j]));
      ushort b = f2bf(phi_f(k1a[j]));
      zacc[j] += bf2f(a) + bf2f(b);   // Z consistent with bf16-rounded MFMA operand
      *(unsigned*)&ktl[(db + j) * LDK + 2 * p] = (unsigned)a | ((unsigned)b << 16);
      ushort x = f2bf(v0a[j]);
      ushort y = f2bf(v1a[j]);
      *(unsigned*)&vtl[(db + j) * LDK + 2 * p] = (unsigned)x | ((unsigned)y << 16);
    }
    __syncthreads();

    bf16x8 bfr[2];
#pragma unroll
    for (int et = 0; et < 2; et++) {
      int e = w * 32 + et * 16 + (lane & 15);
      bfr[et] = *(const bf16x8*)&vtl[e * LDK + kk];
    }
#pragma unroll
    for (int dt = 0; dt < 8; dt++) {
      int dd = dt * 16 + (lane & 15);
      bf16x8 afr = *(const bf16x8*)&ktl[dd * LDK + kk];
      acc[dt][0] = __builtin_amdgcn_mfma_f32_16x16x32_bf16(afr, bfr[0], acc[dt][0], 0, 0, 0);
      acc[dt][1] = __builtin_amdgcn_mfma_f32_16x16x32_bf16(afr, bfr[1], acc[dt][1], 0, 0, 0);
    }
  }

  // write partial KV [d][e] f32
  float* pp = part + (long)wg * (DIM * DIM);
#pragma unroll
  for (int dt = 0; dt < 8; dt++) {
#pragma unroll
    for (int et = 0; et < 2; et++) {
      int e = w * 32 + et * 16 + (lane & 15);
      int r0 = dt * 16 + (lane >> 4) * 4;
#pragma unroll
      for (int r = 0; r < 4; r++)
        pp[(r0 + r) * DIM + e] = acc[dt][et][r];
    }
  }
#pragma unroll
  for (int j = 0; j < 8; j++) atomicAdd(&zl[db + j], zacc[j]);
  __syncthreads();
  if (t < DIM) zpart[(long)wg * DIM + t] = zl[t];
}

// ------------- Reduce v2: parallel, unrolled; emit KV^T (bf16), Z (f32) -----
// grid = BH * 8 blocks; each block owns a 16-row d-tile of one bh.
template<int NCH>
__global__ __launch_bounds__(256) void k_red(
    const float* __restrict__ part, const float* __restrict__ zpart,
    ushort* __restrict__ kvt, float* __restrict__ zout)
{
  __shared__ float kl[16][DIM + 2];
  const int bh = blockIdx.x >> 3;
  const int tile = blockIdx.x & 7;
  const int d0 = tile * 16;
  const int t = threadIdx.x;
  const long pbase = (long)bh * NCH * (DIM * DIM);

  // 16 rows x 128 cols = 512 float4; 2 per thread. NCH independent loads each.
#pragma unroll
  for (int i = 0; i < 2; i++) {
    int f4 = t + i * 256;
    int row = f4 >> 5;          // 0..15
    int c4 = f4 & 31;           // 0..31
    const float4* p4 = (const float4*)(part + pbase + (long)(d0 + row) * DIM + c4 * 4);
    float4 s = {0.f, 0.f, 0.f, 0.f};
#pragma unroll
    for (int cc = 0; cc < NCH; cc++) {
      float4 v = p4[(long)cc * (DIM * DIM / 4)];
      s.x += v.x; s.y += v.y; s.z += v.z; s.w += v.w;
    }
    kl[row][c4 * 4 + 0] = s.x;
    kl[row][c4 * 4 + 1] = s.y;
    kl[row][c4 * 4 + 2] = s.z;
    kl[row][c4 * 4 + 3] = s.w;
  }
  __syncthreads();

  // transpose-emit: kvt[bh][e*128 + d0 + dl], 8 contiguous bf16 per thread
  {
    int e = t >> 1;
    int dl = (t & 1) * 8;
    ushort o[8];
#pragma unroll
    for (int j = 0; j < 8; j++) o[j] = f2bf(kl[dl + j][e]);
    *(uint4*)&kvt[(long)bh * (DIM * DIM) + (long)e * DIM + d0 + dl] = *(uint4*)o;
  }

  if (tile == 0 && t < DIM) {
    float s = 0.f;
#pragma unroll
    for (int cc = 0; cc < NCH; cc++)
      s += zpart[((long)bh * NCH + cc) * DIM + t];
    zout[(long)bh * DIM + t] = s;
  }
}

// --------- Kernel 2: out = (phi(Q) KV) / (phi(Q)·Z + eps) -------------------
#define QB 64
#define LDQ 136   // 128 + 8 pad

__global__ __launch_bounds__(256) void k2_fwd(
    const float* __restrict__ Qg, const ushort* __restrict__ kvt,
    const float* __restrict__ zg, float* __restrict__ outg)
{
  __shared__ ushort ql[QB * LDQ];
  __shared__ ushort kvl[DIM * LDQ];
  __shared__ float zl[DIM];
  __shared__ float dpart[4][QB];
  __shared__ float invd[QB];

  const int bid = blockIdx.x;
  const int bh = bid >> 5;
  const int q0 = (bid & 31) * QB;
  const int t = threadIdx.x;
  const int lane = t & 63;
  const int w = t >> 6;

  if (t < DIM) zl[t] = zg[(long)bh * DIM + t];

  // stage phi(Q) as bf16, row-major
  const float* Qp = Qg + ((long)bh * NQ + q0) * DIM;
#pragma unroll
  for (int i = 0; i < 8; i++) {
    int idx4 = t + i * 256;          // float4 chunk id
    int row = idx4 >> 5;
    int c4 = idx4 & 31;
    float4 v = *(const float4*)(Qp + (long)row * DIM + c4 * 4);
    ushort a = f2bf(phi_f(v.x)), b = f2bf(phi_f(v.y));
    ushort cq = f2bf(phi_f(v.z)), dq = f2bf(phi_f(v.w));
    uint2 pk;
    pk.x = (unsigned)a | ((unsigned)b << 16);
    pk.y = (unsigned)cq | ((unsigned)dq << 16);
    *(uint2*)&ql[row * LDQ + c4 * 4] = pk;
  }
  // stage KV^T (already bf16)
  const ushort* kp = kvt + (long)bh * (DIM * DIM);
#pragma unroll
  for (int i = 0; i < 8; i++) {
    int idx8 = t + i * 256;
    int row = idx8 >> 4;
    int c8 = idx8 & 15;
    uint4 vv = *(const uint4*)(kp + row * DIM + c8 * 8);
    *(uint4*)&kvl[row * LDQ + c8 * 8] = vv;
  }
  __syncthreads();

  // denominator per row
  {
    int row = t & (QB - 1);
    int q4 = t >> 6;
    float s = 0.f;
#pragma unroll
    for (int i = 0; i < 4; i++) {
      int d0 = q4 * 32 + i * 8;
      bf16x8 qv = *(const bf16x8*)&ql[row * LDQ + d0];
#pragma unroll
      for (int j = 0; j < 8; j++)
        s += bf2f((ushort)qv[j]) * zl[d0 + j];
    }
    dpart[q4][row] = s;
  }
  __syncthreads();
  if (t < QB) {
    float den = dpart[0][t] + dpart[1][t] + dpart[2][t] + dpart[3][t] + EPSV;
    invd[t] = 1.f / den;
  }
  __syncthreads();

  // numerator via MFMA: D[q][e] += A[q][d] * B[d][e]
  const int kk = (lane >> 4) * 8;
  const int qrow = w * 16 + (lane & 15);
  f32x4 acc[8];
#pragma unroll
  for (int et = 0; et < 8; et++) acc[et] = (f32x4){0.f, 0.f, 0.f, 0.f};

#pragma unroll
  for (int d0 = 0; d0 < DIM; d0 += 32) {
    bf16x8 afr = *(const bf16x8*)&ql[qrow * LDQ + d0 + kk];
#pragma unroll
    for (int et = 0; et < 8; et++) {
      int e = et * 16 + (lane & 15);
      bf16x8 bfr = *(const bf16x8*)&kvl[e * LDQ + d0 + kk];
      acc[et] = __builtin_amdgcn_mfma_f32_16x16x32_bf16(afr, bfr, acc[et], 0, 0, 0);
    }
  }

  // epilogue: scale by 1/den, store f32
  float* op = outg + ((long)bh * NQ + q0) * DIM;
#pragma unroll
  for (int et = 0; et < 8; et++) {
    int e = et * 16 + (lane & 15);
    int r0 = w * 16 + (lane >> 4) * 4;
#pragma unroll
    for (int r = 0; r < 4; r++) {
      float val = acc[et][r] * invd[r0 + r];
      op[(long)(r0 + r) * DIM + e] = val;
    }
  }
}

extern "C" void kernel_launch(void* const* d_in, const int* in_sizes, int n_in,
                              void* d_out, int out_size, void* d_ws, size_t ws_size,
                              hipStream_t stream) {
  const float* Q  = (const float*)d_in[0];
  const float* Km = (const float*)d_in[1];
  const float* Vm = (const float*)d_in[2];
  float* out = (float*)d_out;

  char* ws = (char*)d_ws;
  ushort* kvt = (ushort*)ws;                                    // 64*16384*2 = 2 MB
  float* zred = (float*)(ws + (size_t)BH * DIM * DIM * 2);      // 32 KB
  size_t fixed = (size_t)BH * DIM * DIM * 2 + (size_t)BH * DIM * 4;

  int nch = 16;
  while (nch > 1) {
    size_t need = fixed + (size_t)BH * nch * DIM * DIM * 4 + (size_t)BH * nch * DIM * 4;
    if (need <= ws_size) break;
    nch >>= 1;
  }
  float* part  = (float*)(ws + fixed);
  float* zpart = part + (size_t)BH * nch * DIM * DIM;
  int ck = NKV / nch;

  k1_kv<<<BH * nch, 256, 0, stream>>>(Km, Vm, part, zpart, nch, ck);

  dim3 rg(BH * 8);
  switch (nch) {
    case 16: k_red<16><<<rg, 256, 0, stream>>>(part, zpart, kvt, zred); break;
    case 8:  k_red<8> <<<rg, 256, 0, stream>>>(part, zpart, kvt, zred); break;
    case 4:  k_red<4> <<<rg, 256, 0, stream>>>(part, zpart, kvt, zred); break;
    case 2:  k_red<2> <<<rg, 256, 0, stream>>>(part, zpart, kvt, zred); break;
    default: k_red<1> <<<rg, 256, 0, stream>>>(part, zpart, kvt, zred); break;
  }

  k2_fwd<<<BH * 32, 256, 0, stream>>>(Q, kvt, zred, out);
}

// Round 3
// 166.484 us; speedup vs baseline: 2.8368x; 1.1729x over previous
//
#include <hip/hip_runtime.h>
#include <hip/hip_bf16.h>

#define BH 64
#define NKV 8192
#define NQ 2048
#define DIM 128
#define EPSV 1e-6f

typedef __attribute__((ext_vector_type(8))) short bf16x8;
typedef __attribute__((ext_vector_type(4))) float f32x4;

__device__ __forceinline__ float phi_f(float x) { return x > 0.f ? x + 1.f : __expf(x); }

__device__ __forceinline__ ushort f2bf(float f) {
  unsigned u = __builtin_bit_cast(unsigned, f);
  u += 0x7FFFu + ((u >> 16) & 1u);   // round-to-nearest-even
  return (ushort)(u >> 16);
}
__device__ __forceinline__ float bf2f(ushort h) {
  unsigned u = ((unsigned)h) << 16;
  return __builtin_bit_cast(float, u);
}

// ---------------- Kernel 1: partial KV = phi(K)^T V and partial Z ------------
// Partials stored bf16, TRANSPOSED [e][d] (matches C-fragment column layout).
#define KT 32
#define LDK 40   // 32 + 8 pad (bf16); 80B row: reads ~2-way

__global__ __launch_bounds__(256, 4) void k1_kv(
    const float* __restrict__ Kg, const float* __restrict__ Vg,
    ushort* __restrict__ part, float* __restrict__ zpart, int nch, int ck)
{
  __shared__ ushort ktl[DIM * LDK];
  __shared__ ushort vtl[DIM * LDK];
  __shared__ float zl[DIM];

  const int wg = blockIdx.x;
  const int bh = wg / nch;
  const int c  = wg - bh * nch;
  const int t  = threadIdx.x;
  const int lane = t & 63;
  const int w  = t >> 6;          // wave 0..3 -> e range w*32..w*32+32
  const int p  = t >> 4;          // row-pair 0..15
  const int db = (t & 15) * 8;    // d base for staging

  const long base = (long)bh * NKV * DIM + (long)c * ck * DIM;
  const float* Kp = Kg + base;
  const float* Vp = Vg + base;

  if (t < DIM) zl[t] = 0.f;
  __syncthreads();

  f32x4 acc[8][2];
#pragma unroll
  for (int i = 0; i < 8; i++) {
    acc[i][0] = (f32x4){0.f, 0.f, 0.f, 0.f};
    acc[i][1] = (f32x4){0.f, 0.f, 0.f, 0.f};
  }
  float zacc[8];
#pragma unroll
  for (int j = 0; j < 8; j++) zacc[j] = 0.f;

  const int kk = (lane >> 4) * 8;

  for (int k0 = 0; k0 < ck; k0 += KT) {
    const float* kr = Kp + (long)(k0 + 2 * p) * DIM + db;
    float4 ka0 = *(const float4*)(kr);
    float4 ka1 = *(const float4*)(kr + 4);
    float4 kb0 = *(const float4*)(kr + DIM);
    float4 kb1 = *(const float4*)(kr + DIM + 4);
    const float* vr = Vp + (long)(k0 + 2 * p) * DIM + db;
    float4 va0 = *(const float4*)(vr);
    float4 va1 = *(const float4*)(vr + 4);
    float4 vb0 = *(const float4*)(vr + DIM);
    float4 vb1 = *(const float4*)(vr + DIM + 4);

    float k0a[8] = {ka0.x, ka0.y, ka0.z, ka0.w, ka1.x, ka1.y, ka1.z, ka1.w};
    float k1a[8] = {kb0.x, kb0.y, kb0.z, kb0.w, kb1.x, kb1.y, kb1.z, kb1.w};
    float v0a[8] = {va0.x, va0.y, va0.z, va0.w, va1.x, va1.y, va1.z, va1.w};
    float v1a[8] = {vb0.x, vb0.y, vb0.z, vb0.w, vb1.x, vb1.y, vb1.z, vb1.w};

    __syncthreads();   // previous iteration's LDS reads done

#pragma unroll
    for (int j = 0; j < 8; j++) {
      int row = db + j;
      int sw = ((row >> 3) & 3) << 3;            // 16B-granule XOR swizzle
      int col = (2 * p) ^ sw;
      ushort a = f2bf(phi_f(k0a[j]));
      ushort b = f2bf(phi_f(k1a[j]));
      zacc[j] += bf2f(a) + bf2f(b);   // Z consistent with bf16-rounded MFMA operand
      *(unsigned*)&ktl[row * LDK + col] = (unsigned)a | ((unsigned)b << 16);
      ushort x = f2bf(v0a[j]);
      ushort y = f2bf(v1a[j]);
      *(unsigned*)&vtl[row * LDK + col] = (unsigned)x | ((unsigned)y << 16);
    }
    __syncthreads();

    bf16x8 bfr[2];
#pragma unroll
    for (int et = 0; et < 2; et++) {
      int e = w * 32 + et * 16 + (lane & 15);
      int kk2 = kk ^ (((e >> 3) & 3) << 3);
      bfr[et] = *(const bf16x8*)&vtl[e * LDK + kk2];
    }
#pragma unroll
    for (int dt = 0; dt < 8; dt++) {
      int dd = dt * 16 + (lane & 15);
      int kk2 = kk ^ (((dd >> 3) & 3) << 3);
      bf16x8 afr = *(const bf16x8*)&ktl[dd * LDK + kk2];
      acc[dt][0] = __builtin_amdgcn_mfma_f32_16x16x32_bf16(afr, bfr[0], acc[dt][0], 0, 0, 0);
      acc[dt][1] = __builtin_amdgcn_mfma_f32_16x16x32_bf16(afr, bfr[1], acc[dt][1], 0, 0, 0);
    }
  }

  // write partial KV transposed [e][d], bf16, vectorized 4-d per store
  ushort* pp = part + (long)wg * (DIM * DIM);
#pragma unroll
  for (int dt = 0; dt < 8; dt++) {
    int d0 = dt * 16 + (lane >> 4) * 4;
#pragma unroll
    for (int et = 0; et < 2; et++) {
      int e = w * 32 + et * 16 + (lane & 15);
      ushort o[4];
#pragma unroll
      for (int r = 0; r < 4; r++) o[r] = f2bf(acc[dt][et][r]);
      *(uint2*)&pp[(long)e * DIM + d0] = *(uint2*)o;
    }
  }
#pragma unroll
  for (int j = 0; j < 8; j++) atomicAdd(&zl[db + j], zacc[j]);
  __syncthreads();
  if (t < DIM) zpart[(long)wg * DIM + t] = zl[t];
}

// ------------- Reduce: sum bf16 partials (already [e][d]); emit kvt, Z ------
template<int NCH>
__global__ __launch_bounds__(256) void k_red(
    const ushort* __restrict__ part, const float* __restrict__ zpart,
    ushort* __restrict__ kvt, float* __restrict__ zout)
{
  const int bh = blockIdx.x >> 2;
  const int quad = blockIdx.x & 3;
  const int t = threadIdx.x;
  const long pbase = (long)bh * NCH * (DIM * DIM);

  // per bh: 16384 bf16 = 2048 uint4; per quad-block 512; per thread 2
#pragma unroll
  for (int i = 0; i < 2; i++) {
    int u4 = quad * 512 + t + i * 256;
    long off = pbase + (long)u4 * 8;
    float s[8] = {0.f, 0.f, 0.f, 0.f, 0.f, 0.f, 0.f, 0.f};
#pragma unroll
    for (int cc = 0; cc < NCH; cc++) {
      uint4 v = *(const uint4*)&part[off + (long)cc * (DIM * DIM)];
      unsigned ws_[4] = {v.x, v.y, v.z, v.w};
#pragma unroll
      for (int h = 0; h < 4; h++) {
        s[2 * h]     += bf2f((ushort)(ws_[h] & 0xFFFFu));
        s[2 * h + 1] += bf2f((ushort)(ws_[h] >> 16));
      }
    }
    unsigned o[4];
#pragma unroll
    for (int h = 0; h < 4; h++)
      o[h] = (unsigned)f2bf(s[2 * h]) | ((unsigned)f2bf(s[2 * h + 1]) << 16);
    *(uint4*)&kvt[(long)bh * (DIM * DIM) + (long)u4 * 8] =
        make_uint4(o[0], o[1], o[2], o[3]);
  }

  if (quad == 0 && t < DIM) {
    float s = 0.f;
#pragma unroll
    for (int cc = 0; cc < NCH; cc++)
      s += zpart[((long)bh * NCH + cc) * DIM + t];
    zout[(long)bh * DIM + t] = s;
  }
}

// --------- Kernel 2: out = (phi(Q) KV) / (phi(Q)·Z + eps) -------------------
#define QB 64
#define LDQ 136   // 128 + 8 pad

__global__ __launch_bounds__(256) void k2_fwd(
    const float* __restrict__ Qg, const ushort* __restrict__ kvt,
    const float* __restrict__ zg, float* __restrict__ outg)
{
  __shared__ ushort ql[QB * LDQ];
  __shared__ ushort kvl[DIM * LDQ];
  __shared__ float zl[DIM];
  __shared__ float dpart[4][QB];
  __shared__ float invd[QB];

  const int bid = blockIdx.x;
  const int bh = bid >> 5;
  const int q0 = (bid & 31) * QB;
  const int t = threadIdx.x;
  const int lane = t & 63;
  const int w = t >> 6;

  if (t < DIM) zl[t] = zg[(long)bh * DIM + t];

  // stage phi(Q) as bf16, row-major
  const float* Qp = Qg + ((long)bh * NQ + q0) * DIM;
#pragma unroll
  for (int i = 0; i < 8; i++) {
    int idx4 = t + i * 256;          // float4 chunk id
    int row = idx4 >> 5;
    int c4 = idx4 & 31;
    float4 v = *(const float4*)(Qp + (long)row * DIM + c4 * 4);
    ushort a = f2bf(phi_f(v.x)), b = f2bf(phi_f(v.y));
    ushort cq = f2bf(phi_f(v.z)), dq = f2bf(phi_f(v.w));
    uint2 pk;
    pk.x = (unsigned)a | ((unsigned)b << 16);
    pk.y = (unsigned)cq | ((unsigned)dq << 16);
    *(uint2*)&ql[row * LDQ + c4 * 4] = pk;
  }
  // stage KV^T (already bf16)
  const ushort* kp = kvt + (long)bh * (DIM * DIM);
#pragma unroll
  for (int i = 0; i < 8; i++) {
    int idx8 = t + i * 256;
    int row = idx8 >> 4;
    int c8 = idx8 & 15;
    uint4 vv = *(const uint4*)(kp + row * DIM + c8 * 8);
    *(uint4*)&kvl[row * LDQ + c8 * 8] = vv;
  }
  __syncthreads();

  // denominator per row
  {
    int row = t & (QB - 1);
    int q4 = t >> 6;
    float s = 0.f;
#pragma unroll
    for (int i = 0; i < 4; i++) {
      int d0 = q4 * 32 + i * 8;
      bf16x8 qv = *(const bf16x8*)&ql[row * LDQ + d0];
#pragma unroll
      for (int j = 0; j < 8; j++)
        s += bf2f((ushort)qv[j]) * zl[d0 + j];
    }
    dpart[q4][row] = s;
  }
  __syncthreads();
  if (t < QB) {
    float den = dpart[0][t] + dpart[1][t] + dpart[2][t] + dpart[3][t] + EPSV;
    invd[t] = 1.f / den;
  }
  __syncthreads();

  // numerator via MFMA: D[q][e] += A[q][d] * B[d][e]
  const int kk = (lane >> 4) * 8;
  const int qrow = w * 16 + (lane & 15);
  f32x4 acc[8];
#pragma unroll
  for (int et = 0; et < 8; et++) acc[et] = (f32x4){0.f, 0.f, 0.f, 0.f};

#pragma unroll
  for (int d0 = 0; d0 < DIM; d0 += 32) {
    bf16x8 afr = *(const bf16x8*)&ql[qrow * LDQ + d0 + kk];
#pragma unroll
    for (int et = 0; et < 8; et++) {
      int e = et * 16 + (lane & 15);
      bf16x8 bfr = *(const bf16x8*)&kvl[e * LDQ + d0 + kk];
      acc[et] = __builtin_amdgcn_mfma_f32_16x16x32_bf16(afr, bfr, acc[et], 0, 0, 0);
    }
  }

  // epilogue: scale by 1/den, store f32
  float* op = outg + ((long)bh * NQ + q0) * DIM;
#pragma unroll
  for (int et = 0; et < 8; et++) {
    int e = et * 16 + (lane & 15);
    int r0 = w * 16 + (lane >> 4) * 4;
#pragma unroll
    for (int r = 0; r < 4; r++) {
      float val = acc[et][r] * invd[r0 + r];
      op[(long)(r0 + r) * DIM + e] = val;
    }
  }
}

extern "C" void kernel_launch(void* const* d_in, const int* in_sizes, int n_in,
                              void* d_out, int out_size, void* d_ws, size_t ws_size,
                              hipStream_t stream) {
  const float* Q  = (const float*)d_in[0];
  const float* Km = (const float*)d_in[1];
  const float* Vm = (const float*)d_in[2];
  float* out = (float*)d_out;

  char* ws = (char*)d_ws;
  ushort* kvt = (ushort*)ws;                                    // 64*16384*2 = 2 MB
  float* zred = (float*)(ws + (size_t)BH * DIM * DIM * 2);      // 32 KB
  size_t fixed = (size_t)BH * DIM * DIM * 2 + (size_t)BH * DIM * 4;

  int nch = 16;
  while (nch > 1) {
    size_t need = fixed + (size_t)BH * nch * DIM * DIM * 2 + (size_t)BH * nch * DIM * 4;
    if (need <= ws_size) break;
    nch >>= 1;
  }
  ushort* partb = (ushort*)(ws + fixed);
  float* zpart = (float*)(ws + fixed + (size_t)BH * nch * DIM * DIM * 2);
  int ck = NKV / nch;

  k1_kv<<<BH * nch, 256, 0, stream>>>(Km, Vm, partb, zpart, nch, ck);

  dim3 rg(BH * 4);
  switch (nch) {
    case 16: k_red<16><<<rg, 256, 0, stream>>>(partb, zpart, kvt, zred); break;
    case 8:  k_red<8> <<<rg, 256, 0, stream>>>(partb, zpart, kvt, zred); break;
    case 4:  k_red<4> <<<rg, 256, 0, stream>>>(partb, zpart, kvt, zred); break;
    case 2:  k_red<2> <<<rg, 256, 0, stream>>>(partb, zpart, kvt, zred); break;
    default: k_red<1> <<<rg, 256, 0, stream>>>(partb, zpart, kvt, zred); break;
  }

  k2_fwd<<<BH * 32, 256, 0, stream>>>(Q, kvt, zred, out);
}